// Round 9
// baseline (15.468 us; speedup 1.0000x reference)
//
#include <hip/hip_runtime.h>

#define BATCH 256
#define NV    5000
#define NCLS  20000
#define G     4                 // batch rows per block (interleaved by 4 in LDS)
#define NT    512               // 8 waves/block; 80 KB LDS -> 2 blocks/CU = 16 waves/CU
#define NCH   8                 // clause chunks
#define CCH   (NCLS / NCH)      // 2500
#define NBLK  (NCH * BATCH / G) // 512 blocks

// Horner over the 3 selector bits; f-deltas precomputed (shared across rows).
__device__ __forceinline__ float eval_c(float f0, float d0, float f2, float d1,
                                        float f4, float d2, float f6, float d3,
                                        float p0, float p1, float p2) {
    float t0 = fmaf(d0, p2, f0);
    float t1 = fmaf(d1, p2, f2);
    float t2 = fmaf(d2, p2, f4);
    float t3 = fmaf(d3, p2, f6);
    float u0 = fmaf(t1 - t0, p1, t0);
    float u1 = fmaf(t3 - t2, p1, t2);
    return fmaf(u1 - u0, p0, u0);
}

// R2-champion body, single dispatch: block (bg = blk & 63, cs = blk >> 6),
// 4 rows x 2500 clauses per block, result accumulated into out via atomicAdd
// (out zeroed each call by the memset node enqueued before this kernel).
__global__ __launch_bounds__(NT)
void bmn_main(const float* __restrict__ x,
              const int*   __restrict__ vars,
              const float* __restrict__ factors,
              float* __restrict__ out) {
    __shared__ float xs[NV * G];          // 80 KB: xs[v*4 + g]
    const int bg  = blockIdx.x & (BATCH / G - 1);
    const int cs  = blockIdx.x >> 6;
    const int tid = threadIdx.x;

    const float* xr = x + bg * G * NV;
    for (int i = tid; i < NV; i += NT) {
        float4 v;
        v.x = xr[i];
        v.y = xr[i + NV];
        v.z = xr[i + 2 * NV];
        v.w = xr[i + 3 * NV];
        *reinterpret_cast<float4*>(&xs[i * 4]) = v;   // consecutive b128: conflict-free
    }
    __syncthreads();

    float4 acc = make_float4(0.f, 0.f, 0.f, 0.f);
    const int cbase = cs * CCH;
    const int cend  = cbase + CCH;
    for (int c = cbase + tid; c < cend; c += NT) {
        const int v0 = vars[c * 3 + 0];
        const int v1 = vars[c * 3 + 1];
        const int v2 = vars[c * 3 + 2];
        const float4 fa = *reinterpret_cast<const float4*>(factors + c * 8);
        const float4 fb = *reinterpret_cast<const float4*>(factors + c * 8 + 4);
        const float4 p0 = *reinterpret_cast<const float4*>(&xs[v0 * 4]);
        const float4 p1 = *reinterpret_cast<const float4*>(&xs[v1 * 4]);
        const float4 p2 = *reinterpret_cast<const float4*>(&xs[v2 * 4]);
        const float d0 = fa.y - fa.x, d1 = fa.w - fa.z;
        const float d2 = fb.y - fb.x, d3 = fb.w - fb.z;
        acc.x += eval_c(fa.x, d0, fa.z, d1, fb.x, d2, fb.z, d3, p0.x, p1.x, p2.x);
        acc.y += eval_c(fa.x, d0, fa.z, d1, fb.x, d2, fb.z, d3, p0.y, p1.y, p2.y);
        acc.z += eval_c(fa.x, d0, fa.z, d1, fb.x, d2, fb.z, d3, p0.z, p1.z, p2.z);
        acc.w += eval_c(fa.x, d0, fa.z, d1, fb.x, d2, fb.z, d3, p0.w, p1.w, p2.w);
    }

    // wave reduce (64 lanes)
    for (int off = 32; off; off >>= 1) {
        acc.x += __shfl_down(acc.x, off, 64);
        acc.y += __shfl_down(acc.y, off, 64);
        acc.z += __shfl_down(acc.z, off, 64);
        acc.w += __shfl_down(acc.w, off, 64);
    }
    __shared__ float red[NT / 64][G];
    if ((tid & 63) == 0) {
        const int w = tid >> 6;
        red[w][0] = acc.x; red[w][1] = acc.y; red[w][2] = acc.z; red[w][3] = acc.w;
    }
    __syncthreads();
    if (tid < G) {
        float s = 0.f;
        #pragma unroll
        for (int w = 0; w < NT / 64; ++w) s += red[w][tid];
        atomicAdd(&out[bg * G + tid], s);   // 8 contributions per output row
    }
}

extern "C" void kernel_launch(void* const* d_in, const int* in_sizes, int n_in,
                              void* d_out, int out_size, void* d_ws, size_t ws_size,
                              hipStream_t stream) {
    const float* x       = (const float*)d_in[0];
    // d_in[1] = binary_combinations (bit order hard-coded; verified rounds 1-8)
    const int*   vars    = (const int*)d_in[2];
    const float* factors = (const float*)d_in[3];
    float* out = (float*)d_out;

    hipMemsetAsync(out, 0, (size_t)BATCH * sizeof(float), stream);  // capturable node
    bmn_main<<<dim3(NBLK), NT, 0, stream>>>(x, vars, factors, out);
}

// Round 10
// 12.717 us; speedup vs baseline: 1.2163x; 1.2163x over previous
//
#include <hip/hip_runtime.h>

#define BATCH 256
#define NV    5000
#define NCLS  20000
#define G     4           // batch rows per block (interleaved by 4 in LDS)
#define NT    512         // 8 waves/block; 80 KB LDS -> 2 blocks/CU = 16 waves/CU
#define NCH   8           // clause chunks; grid = 64 x 8 = 512 blocks

// Horner over the 3 selector bits; f-deltas precomputed (shared across rows).
__device__ __forceinline__ float eval_c(float f0, float d0, float f2, float d1,
                                        float f4, float d2, float f6, float d3,
                                        float p0, float p1, float p2) {
    float t0 = fmaf(d0, p2, f0);
    float t1 = fmaf(d1, p2, f2);
    float t2 = fmaf(d2, p2, f4);
    float t3 = fmaf(d3, p2, f6);
    float u0 = fmaf(t1 - t0, p1, t0);
    float u1 = fmaf(t3 - t2, p1, t2);
    return fmaf(u1 - u0, p0, u0);
}

// Block (bg, cs): batch rows [bg*G, bg*G+G), clause chunk cs of size cchunk.
// R2-champion body + int3 vars load + depth-1 in-loop software pipeline.
__global__ __launch_bounds__(NT)
void bmn_main(const float* __restrict__ x,
              const int*   __restrict__ vars,
              const float* __restrict__ factors,
              float* __restrict__ outbuf,
              int cchunk) {
    __shared__ float xs[NV * G];          // 80 KB: xs[v*4 + g]
    const int bg  = blockIdx.x;
    const int cs  = blockIdx.y;
    const int tid = threadIdx.x;

    const float* xr = x + bg * G * NV;
    for (int i = tid; i < NV; i += NT) {
        float4 v;
        v.x = xr[i];
        v.y = xr[i + NV];
        v.z = xr[i + 2 * NV];
        v.w = xr[i + 3 * NV];
        *reinterpret_cast<float4*>(&xs[i * 4]) = v;   // consecutive b128: conflict-free
    }
    __syncthreads();

    float4 acc = make_float4(0.f, 0.f, 0.f, 0.f);
    const int cbase = cs * cchunk;
    const int cend  = cbase + cchunk;
    int c = cbase + tid;
    if (c < cend) {
        // prologue: issue iteration 0's clause loads
        int3   vv = *reinterpret_cast<const int3*>(vars + c * 3);
        float4 fa = *reinterpret_cast<const float4*>(factors + c * 8);
        float4 fb = *reinterpret_cast<const float4*>(factors + c * 8 + 4);
        for (;;) {
            // issue NEXT iteration's loads before consuming current (depth-1 pipeline)
            const int  cn   = c + NT;
            const bool more = (cn < cend);
            int3   vn; float4 fan, fbn;
            if (more) {
                vn  = *reinterpret_cast<const int3*>(vars + cn * 3);
                fan = *reinterpret_cast<const float4*>(factors + cn * 8);
                fbn = *reinterpret_cast<const float4*>(factors + cn * 8 + 4);
            }
            // consume current clause
            const float4 p0 = *reinterpret_cast<const float4*>(&xs[vv.x * 4]);
            const float4 p1 = *reinterpret_cast<const float4*>(&xs[vv.y * 4]);
            const float4 p2 = *reinterpret_cast<const float4*>(&xs[vv.z * 4]);
            const float d0 = fa.y - fa.x, d1 = fa.w - fa.z;
            const float d2 = fb.y - fb.x, d3 = fb.w - fb.z;
            acc.x += eval_c(fa.x, d0, fa.z, d1, fb.x, d2, fb.z, d3, p0.x, p1.x, p2.x);
            acc.y += eval_c(fa.x, d0, fa.z, d1, fb.x, d2, fb.z, d3, p0.y, p1.y, p2.y);
            acc.z += eval_c(fa.x, d0, fa.z, d1, fb.x, d2, fb.z, d3, p0.z, p1.z, p2.z);
            acc.w += eval_c(fa.x, d0, fa.z, d1, fb.x, d2, fb.z, d3, p0.w, p1.w, p2.w);
            if (!more) break;
            c = cn; vv = vn; fa = fan; fb = fbn;
        }
    }

    // wave reduce (64 lanes)
    for (int off = 32; off; off >>= 1) {
        acc.x += __shfl_down(acc.x, off, 64);
        acc.y += __shfl_down(acc.y, off, 64);
        acc.z += __shfl_down(acc.z, off, 64);
        acc.w += __shfl_down(acc.w, off, 64);
    }
    __shared__ float red[NT / 64][G];
    if ((tid & 63) == 0) {
        const int w = tid >> 6;
        red[w][0] = acc.x; red[w][1] = acc.y; red[w][2] = acc.z; red[w][3] = acc.w;
    }
    __syncthreads();
    if (tid < G) {
        float s = 0.f;
        #pragma unroll
        for (int w = 0; w < NT / 64; ++w) s += red[w][tid];
        outbuf[cs * BATCH + bg * G + tid] = s;
    }
}

__global__ __launch_bounds__(BATCH)
void bmn_reduce(const float* __restrict__ ws, float* __restrict__ out) {
    const int b = threadIdx.x;            // coalesced in b
    float s = 0.f;
    #pragma unroll
    for (int cs = 0; cs < NCH; ++cs) s += ws[cs * BATCH + b];
    out[b] = s;
}

extern "C" void kernel_launch(void* const* d_in, const int* in_sizes, int n_in,
                              void* d_out, int out_size, void* d_ws, size_t ws_size,
                              hipStream_t stream) {
    const float* x       = (const float*)d_in[0];
    // d_in[1] = binary_combinations (bit order hard-coded; verified rounds 1-9)
    const int*   vars    = (const int*)d_in[2];
    const float* factors = (const float*)d_in[3];
    float* out = (float*)d_out;

    if (ws_size >= (size_t)(NCH * BATCH) * sizeof(float)) {
        float* ws = (float*)d_ws;
        bmn_main<<<dim3(BATCH / G, NCH), NT, 0, stream>>>(x, vars, factors, ws, NCLS / NCH);
        bmn_reduce<<<1, BATCH, 0, stream>>>(ws, out);
    } else {
        // fallback: single chunk writes final sums directly (correct, slower)
        bmn_main<<<dim3(BATCH / G, 1), NT, 0, stream>>>(x, vars, factors, out, NCLS);
    }
}